// Round 5
// baseline (146.653 us; speedup 1.0000x reference)
//
#include <hip/hip_runtime.h>
#include <math.h>

// Problem constants (fixed by setup_inputs): B=4, H=W=D=128, C=2, fp32.
#define BN 4
#define HN 128
#define WN 128
#define DN 128

// Tiny pre-kernel: theta fp32 -> fp64 in d_ws. Main kernel then reads theta
// as uniform double via s_load (b is block-uniform), saving 12 v_cvt_f64_f32
// per thread. Runs every kernel_launch (d_ws is re-poisoned each call).
__global__ void theta_cvt_kernel(const float* __restrict__ theta,
                                 double* __restrict__ thd) {
    const int t = threadIdx.x;
    if (t < BN * 12) thd[t] = (double)theta[t];
}

// Block = 16(j) x 32(k) tile at fixed (b,i); 256 threads, 2 voxels/thread
// along k (independent chains -> gather-latency hiding). Lanes jj-fastest
// (j drives x, the contiguous axis of idx = b*H*W*D + y*W + z*(W*H) + x);
// output wants k-fastest -> LDS transpose before the store.
//
// Gather-pair trick: the 8 taps come in 4 pairs at adjacent x, each voxel is
// float2, so one 16B float4 load fetches a pair; the (x0,x1) clip cases
// ((0,0),(127,127)) are folded into x-weights wxl/wxh instead of cndmask'ing
// 8 float2 values (saves ~16 cndmask + ~32 fp32 ops/voxel).
//
// Coordinate path in DOUBLE to mirror the harness's NumPy float64 reference
// (clip convention is discontinuous at edges; fp32 coord math flips boundary
// voxels -> absmax 2.1 in round 1). Do NOT restructure the fp64 chain.
__global__ __launch_bounds__(256) void st_trilerp_kernel(
    const float* __restrict__ image,   // [B*H*W*D, 2] viewed flat
    const double* __restrict__ thd,    // [B, 12] fp64 (from theta_cvt_kernel)
    float* __restrict__ out)           // [B*H*W*D, 2]
{
    const int bi = blockIdx.z;         // b*H + i  (uniform per block)
    const int b  = bi >> 7;
    const int i  = bi & (HN - 1);
    const int j0 = blockIdx.y << 4;
    const int k0 = blockIdx.x << 5;

    const int tid = threadIdx.x;
    const int jj  = tid & 15;          // x-axis fastest across lanes
    const int kk0 = tid >> 4;          // 0..15; second voxel at kk0+16
    const int j = j0 + jj;

    const double step = 2.0 / 127.0;   // np.linspace(-1,1,128): v=i*step-1
    const double X = (j == WN - 1) ? 1.0 : (double)j * step - 1.0;
    const double Y = (i == HN - 1) ? 1.0 : (double)i * step - 1.0;

    const double* th = thd + b * 12;   // uniform -> s_load double pairs

    __shared__ float2 tile[32][17];    // pitch 17 breaks pow-2 stride
    const float2* __restrict__ img2 = (const float2*)image;
    const int base = b * (HN * WN * DN);

#pragma unroll
    for (int v = 0; v < 2; ++v) {
        const int kk = kk0 + v * 16;
        const int k = k0 + kk;
        const double Z = (k == DN - 1) ? 1.0 : (double)k * step - 1.0;

        // einsum in fp64, sequential accumulation order (matches np)
        const double xt = ((th[0] * X + th[1] * Y) + th[2]  * Z) + th[3];
        const double yt = ((th[4] * X + th[5] * Y) + th[6]  * Z) + th[7];
        const double zt = ((th[8] * X + th[9] * Y) + th[10] * Z) + th[11];

        // map [-1,1] -> pixel coords using FULL extent (original convention)
        const double x = (0.5 * (xt + 1.0)) * (double)WN;
        const double y = (0.5 * (yt + 1.0)) * (double)HN;
        const double z = (0.5 * (zt + 1.0)) * (double)DN;

        // floor, +1, then clip (x1/y1/z1 derive from UNclipped +1)
        const int x0u = (int)floor(x);
        const int y0u = (int)floor(y);
        const int z0u = (int)floor(z);
        const int x0 = min(max(x0u,     0), WN - 1);
        const int x1 = min(max(x0u + 1, 0), WN - 1);
        const int y0 = min(max(y0u,     0), HN - 1);
        const int y1 = min(max(y0u + 1, 0), HN - 1);
        const int z0 = min(max(z0u,     0), DN - 1);
        const int z1 = min(max(z0u + 1, 0), DN - 1);

        const int b00 = base + y0 * WN + z0 * (WN * HN);
        const int b10 = base + y1 * WN + z0 * (WN * HN);
        const int b01 = base + y0 * WN + z1 * (WN * HN);
        const int b11 = base + y1 * WN + z1 * (WN * HN);

        // (x0,x1) is (v,v+1) for v in 0..126, or (0,0), or (127,127).
        const int xb = min(x0, WN - 2);            // 0..126, pair in-bounds
        const bool lo0 = (x0 == xb);               // tap x0 from low half?
        const bool lo1 = (x1 == xb);               // tap x1 from low half?

        const float4 q00 = *(const float4*)(img2 + b00 + xb);
        const float4 q10 = *(const float4*)(img2 + b10 + xb);
        const float4 q01 = *(const float4*)(img2 + b01 + xb);
        const float4 q11 = *(const float4*)(img2 + b11 + xb);

        // weight FACTORS in fp64 (cancellation must match np), rest in fp32
        const float wx0 = (float)((double)x1 - x), wx1 = (float)(x - (double)x0);
        const float wy0 = (float)((double)y1 - y), wy1 = (float)(y - (double)y0);
        const float wz0 = (float)((double)z1 - z);
        const float wzA = (float)(z1 - z0);

        // fold x-clip selection into the x-weights
        const float wxl = (lo0 ? wx0 : 0.0f) + (lo1 ? wx1 : 0.0f);
        const float wxh = (lo0 ? 0.0f : wx0) + (lo1 ? 0.0f : wx1);

        const float s00 = wy0 * wz0;
        const float s10 = wy1 * wz0;
        const float s01 = wy0 * wzA;
        const float s11 = wy1 * wzA;

        float2 o;
        o.x = s00 * (wxl * q00.x + wxh * q00.z)
            + s10 * (wxl * q10.x + wxh * q10.z)
            + s01 * (wxl * q01.x + wxh * q01.z)
            + s11 * (wxl * q11.x + wxh * q11.z);
        o.y = s00 * (wxl * q00.y + wxh * q00.w)
            + s10 * (wxl * q10.y + wxh * q10.w)
            + s01 * (wxl * q01.y + wxh * q01.w)
            + s11 * (wxl * q11.y + wxh * q11.w);

        tile[kk][jj] = o;
    }

    __syncthreads();

    // write phase: k fastest across lanes for coalesced 256B runs
#pragma unroll
    for (int v = 0; v < 2; ++v) {
        const int wid = tid + v * 256;
        const int kw = wid & 31;
        const int jw = wid >> 5;                   // 0..15
        const int oidx = (bi * WN + (j0 + jw)) * DN + (k0 + kw);
        ((float2*)out)[oidx] = tile[kw][jw];
    }
}

extern "C" void kernel_launch(void* const* d_in, const int* in_sizes, int n_in,
                              void* d_out, int out_size, void* d_ws, size_t ws_size,
                              hipStream_t stream) {
    const float* image = (const float*)d_in[0];
    const float* theta = (const float*)d_in[1];
    float* out = (float*)d_out;
    double* thd = (double*)d_ws;                   // 48 doubles = 384 B

    theta_cvt_kernel<<<1, 64, 0, stream>>>(theta, thd);

    dim3 grid(DN / 32, WN / 16, BN * HN);          // (4, 8, 512) = 16384
    st_trilerp_kernel<<<grid, 256, 0, stream>>>(image, thd, out);
}